// Round 4
// baseline (3007.288 us; speedup 1.0000x reference)
//
#include <hip/hip_runtime.h>
#include <hip/hip_fp16.h>

#define UNITS 128
#define IN_DIM 256
#define BK 32
#define BSHIFT 7                    // 128 rows per bucket
#define BROWS (1 << BSHIFT)
#define MAXBUCKETS 1024
#define BIN_CHUNK 4096              // edges per binning block

// ---------------------------------------------------------------------------
// GEMM: h = x @ W (fp32 compute, fp16 output).
// Block tile 64 rows x 128 cols, BK=32; per thread 8 rows x 4 cols.
// ---------------------------------------------------------------------------
__global__ __launch_bounds__(256) void gemm_xw_kernel(
    const float* __restrict__ x, const float* __restrict__ W,
    __half* __restrict__ h, int n_nodes) {
  __shared__ float Wt[BK * UNITS];   // 16 KiB  [kk][u]
  __shared__ float Xt[BK * 64];      // 8 KiB   [kk][r]  (transposed)

  const int tid = threadIdx.x;
  const int g   = tid & 31;          // col group (4 cols)
  const int tr  = tid >> 5;          // 0..7 (8 rows each)
  const int row0 = blockIdx.x * 64;

  float4 acc[8];
#pragma unroll
  for (int i = 0; i < 8; ++i) acc[i] = make_float4(0.f, 0.f, 0.f, 0.f);

  const int sr = tid & 63;
  const int cg = tid >> 6;
  const int grow = row0 + sr;

  for (int k0 = 0; k0 < IN_DIM; k0 += BK) {
    {
      const float4* Wg = (const float4*)(W + (size_t)k0 * UNITS);
      float4* Ws = (float4*)Wt;
#pragma unroll
      for (int i = 0; i < 4; ++i) Ws[tid + i * 256] = Wg[tid + i * 256];
    }
#pragma unroll
    for (int i = 0; i < 2; ++i) {
      const int c4 = cg + i * 4;
      float4 v = make_float4(0.f, 0.f, 0.f, 0.f);
      if (grow < n_nodes)
        v = *(const float4*)(x + (size_t)grow * IN_DIM + k0 + c4 * 4);
      Xt[(c4 * 4 + 0) * 64 + sr] = v.x;
      Xt[(c4 * 4 + 1) * 64 + sr] = v.y;
      Xt[(c4 * 4 + 2) * 64 + sr] = v.z;
      Xt[(c4 * 4 + 3) * 64 + sr] = v.w;
    }
    __syncthreads();

#pragma unroll 8
    for (int kk = 0; kk < BK; ++kk) {
      const float4 w  = ((const float4*)Wt)[kk * 32 + g];
      const float4 a0 = ((const float4*)Xt)[kk * 16 + tr * 2];
      const float4 a1 = ((const float4*)Xt)[kk * 16 + tr * 2 + 1];
      acc[0].x = fmaf(a0.x, w.x, acc[0].x); acc[0].y = fmaf(a0.x, w.y, acc[0].y);
      acc[0].z = fmaf(a0.x, w.z, acc[0].z); acc[0].w = fmaf(a0.x, w.w, acc[0].w);
      acc[1].x = fmaf(a0.y, w.x, acc[1].x); acc[1].y = fmaf(a0.y, w.y, acc[1].y);
      acc[1].z = fmaf(a0.y, w.z, acc[1].z); acc[1].w = fmaf(a0.y, w.w, acc[1].w);
      acc[2].x = fmaf(a0.z, w.x, acc[2].x); acc[2].y = fmaf(a0.z, w.y, acc[2].y);
      acc[2].z = fmaf(a0.z, w.z, acc[2].z); acc[2].w = fmaf(a0.z, w.w, acc[2].w);
      acc[3].x = fmaf(a0.w, w.x, acc[3].x); acc[3].y = fmaf(a0.w, w.y, acc[3].y);
      acc[3].z = fmaf(a0.w, w.z, acc[3].z); acc[3].w = fmaf(a0.w, w.w, acc[3].w);
      acc[4].x = fmaf(a1.x, w.x, acc[4].x); acc[4].y = fmaf(a1.x, w.y, acc[4].y);
      acc[4].z = fmaf(a1.x, w.z, acc[4].z); acc[4].w = fmaf(a1.x, w.w, acc[4].w);
      acc[5].x = fmaf(a1.y, w.x, acc[5].x); acc[5].y = fmaf(a1.y, w.y, acc[5].y);
      acc[5].z = fmaf(a1.y, w.z, acc[5].z); acc[5].w = fmaf(a1.y, w.w, acc[5].w);
      acc[6].x = fmaf(a1.z, w.x, acc[6].x); acc[6].y = fmaf(a1.z, w.y, acc[6].y);
      acc[6].z = fmaf(a1.z, w.z, acc[6].z); acc[6].w = fmaf(a1.z, w.w, acc[6].w);
      acc[7].x = fmaf(a1.w, w.x, acc[7].x); acc[7].y = fmaf(a1.w, w.y, acc[7].y);
      acc[7].z = fmaf(a1.w, w.z, acc[7].z); acc[7].w = fmaf(a1.w, w.w, acc[7].w);
    }
    __syncthreads();
  }

#pragma unroll
  for (int i = 0; i < 8; ++i) {
    const int rr = row0 + tr * 8 + i;
    if (rr < n_nodes) {
      union { __half2 h2[2]; uint2 u2; } pk;
      pk.h2[0] = __floats2half2_rn(acc[i].x, acc[i].y);
      pk.h2[1] = __floats2half2_rn(acc[i].z, acc[i].w);
      ((uint2*)(h + (size_t)rr * UNITS))[g] = pk.u2;
    }
  }
}

// ---------------------------------------------------------------------------
// Bucket histogram (LDS-aggregated)
// ---------------------------------------------------------------------------
__global__ __launch_bounds__(256) void bucket_hist_kernel(
    const int* __restrict__ rows, int* __restrict__ bhist,
    int n_edges, int nbuckets) {
  __shared__ int sh[MAXBUCKETS];
  const int tid = threadIdx.x;
  for (int i = tid; i < nbuckets; i += 256) sh[i] = 0;
  __syncthreads();
  const int stride = gridDim.x * blockDim.x;
  for (int e = blockIdx.x * blockDim.x + tid; e < n_edges; e += stride)
    atomicAdd(&sh[rows[e] >> BSHIFT], 1);
  __syncthreads();
  for (int i = tid; i < nbuckets; i += 256) {
    const int c = sh[i];
    if (c) atomicAdd(&bhist[i], c);
  }
}

// ---------------------------------------------------------------------------
// Bucket exclusive scan (single block; nbuckets <= 1024)
// ---------------------------------------------------------------------------
__global__ __launch_bounds__(1024) void bucket_scan_kernel(
    const int* __restrict__ bhist, int* __restrict__ boff,
    int* __restrict__ bcur, int nbuckets) {
  __shared__ int s[1024];
  const int t = threadIdx.x;
  const int v = (t < nbuckets) ? bhist[t] : 0;
  s[t] = v;
  __syncthreads();
  for (int off = 1; off < 1024; off <<= 1) {
    int u = 0;
    if (t >= off) u = s[t - off];
    __syncthreads();
    if (t >= off) s[t] += u;
    __syncthreads();
  }
  if (t < nbuckets) {
    boff[t] = s[t] - v;
    bcur[t] = s[t] - v;
  }
  if (t == 1023) boff[nbuckets] = s[1023];
}

// ---------------------------------------------------------------------------
// Binning: edges -> bucket-major order, packed (row_lo<<17 | col, valbits).
// 3-phase block-local LDS cursor => few global atomics, dense appends.
// ---------------------------------------------------------------------------
__global__ __launch_bounds__(256) void binning_kernel(
    const int* __restrict__ rows, const int* __restrict__ cols,
    const float* __restrict__ vals, int* __restrict__ bcur,
    int2* __restrict__ binned, int n_edges, int nbuckets) {
  __shared__ int sh_hist[MAXBUCKETS];
  __shared__ int sh_base[MAXBUCKETS];
  const int tid = threadIdx.x;
  const int e0 = blockIdx.x * BIN_CHUNK;
  const int e_end = min(e0 + BIN_CHUNK, n_edges);

  for (int i = tid; i < nbuckets; i += 256) sh_hist[i] = 0;
  __syncthreads();
  for (int e = e0 + tid; e < e_end; e += 256)
    atomicAdd(&sh_hist[rows[e] >> BSHIFT], 1);
  __syncthreads();
  for (int i = tid; i < nbuckets; i += 256) {
    const int c = sh_hist[i];
    sh_base[i] = c ? atomicAdd(&bcur[i], c) : 0;
  }
  __syncthreads();
  for (int i = tid; i < nbuckets; i += 256) sh_hist[i] = 0;
  __syncthreads();
  for (int e = e0 + tid; e < e_end; e += 256) {
    const int r = rows[e];
    const int b = r >> BSHIFT;
    const int pos = sh_base[b] + atomicAdd(&sh_hist[b], 1);
    binned[pos] = make_int2(((r & (BROWS - 1)) << 17) | cols[e],
                            __float_as_int(vals[e]));
  }
}

// ---------------------------------------------------------------------------
// Fused aggregate + relu: one bucket (128 rows) per block.
// 64 KiB dynamic-LDS fp32 accumulator, ds_add_f32 atomics, fp16 h gathers.
// ---------------------------------------------------------------------------
__global__ __launch_bounds__(512) void aggregate_kernel(
    const int* __restrict__ boff, const int2* __restrict__ binned,
    const __half* __restrict__ h, float* __restrict__ out, int n_nodes) {
  extern __shared__ float acc[];     // BROWS * UNITS = 16384 floats
  const int tid  = threadIdx.x;
  const int lane = tid & 63;
  const int wave = tid >> 6;         // 0..7
  const int b    = blockIdx.x;
  const int row0 = b << BSHIFT;

  for (int i = tid; i < BROWS * UNITS; i += 512) acc[i] = 0.f;
  __syncthreads();

  const int e0 = boff[b];
  const int e1 = boff[b + 1];

  for (int e = e0 + wave * 2; e < e1; e += 16) {
    const int2 r0 = binned[e];
    const bool two = (e + 1 < e1);
    const int2 r1 = two ? binned[e + 1] : make_int2(0, 0);

    const int   c0  = r0.x & 0x1FFFF;
    const int   rl0 = (r0.x >> 17) & (BROWS - 1);
    const float v0  = __int_as_float(r0.y);
    const __half2 g0 = ((const __half2*)(h + (size_t)c0 * UNITS))[lane];

    const int   c1  = r1.x & 0x1FFFF;
    const int   rl1 = (r1.x >> 17) & (BROWS - 1);
    const float v1  = two ? __int_as_float(r1.y) : 0.f;
    const __half2 g1 = ((const __half2*)(h + (size_t)c1 * UNITS))[lane];

    const float2 f0 = __half22float2(g0);
    atomicAdd(&acc[rl0 * UNITS + lane * 2 + 0], f0.x * v0);
    atomicAdd(&acc[rl0 * UNITS + lane * 2 + 1], f0.y * v0);
    if (two) {
      const float2 f1 = __half22float2(g1);
      atomicAdd(&acc[rl1 * UNITS + lane * 2 + 0], f1.x * v1);
      atomicAdd(&acc[rl1 * UNITS + lane * 2 + 1], f1.y * v1);
    }
  }
  __syncthreads();

  // write out with relu: 128 rows x 32 float4
  for (int i = tid; i < BROWS * (UNITS / 4); i += 512) {
    const int rr = row0 + (i >> 5);
    if (rr < n_nodes) {
      float4 v = ((const float4*)acc)[i];
      v.x = v.x > 0.f ? v.x : 0.f;
      v.y = v.y > 0.f ? v.y : 0.f;
      v.z = v.z > 0.f ? v.z : 0.f;
      v.w = v.w > 0.f ? v.w : 0.f;
      ((float4*)(out + (size_t)rr * UNITS))[i & 31] = v;
    }
  }
}

// ---------------------------------------------------------------------------
extern "C" void kernel_launch(void* const* d_in, const int* in_sizes, int n_in,
                              void* d_out, int out_size, void* d_ws, size_t ws_size,
                              hipStream_t stream) {
  const float* x     = (const float*)d_in[0];
  const float* W     = (const float*)d_in[1];
  const int*   rows  = (const int*)d_in[2];
  const int*   cols  = (const int*)d_in[3];
  const float* vals  = (const float*)d_in[4];
  float*       out   = (float*)d_out;

  const int n_nodes = in_sizes[0] / IN_DIM;   // 100000
  const int n_edges = in_sizes[2];            // 3200000
  const int nbuckets = (n_nodes + BROWS - 1) >> BSHIFT;   // 782

  char* ws = (char*)d_ws;
  size_t off = 0;
  auto alloc = [&](size_t bytes) {
    char* p = ws + off;
    off += (bytes + 511) & ~(size_t)511;
    return p;
  };
  __half* h      = (__half*)alloc((size_t)n_nodes * UNITS * sizeof(__half)); // 25.6MB
  int*    bhist  = (int*)   alloc((size_t)nbuckets * sizeof(int));
  int*    boff   = (int*)   alloc((size_t)(nbuckets + 1) * sizeof(int));
  int*    bcur   = (int*)   alloc((size_t)nbuckets * sizeof(int));
  int2*   binned = (int2*)  alloc((size_t)n_edges * sizeof(int2));           // 25.6MB

  // 1) h = x @ W  (fp16 output)
  gemm_xw_kernel<<<(n_nodes + 63) / 64, 256, 0, stream>>>(x, W, h, n_nodes);

  // 2) bucket CSR build
  hipMemsetAsync(bhist, 0, (size_t)nbuckets * sizeof(int), stream);
  bucket_hist_kernel<<<512, 256, 0, stream>>>(rows, bhist, n_edges, nbuckets);
  bucket_scan_kernel<<<1, 1024, 0, stream>>>(bhist, boff, bcur, nbuckets);
  binning_kernel<<<(n_edges + BIN_CHUNK - 1) / BIN_CHUNK, 256, 0, stream>>>(
      rows, cols, vals, bcur, binned, n_edges, nbuckets);

  // 3) fused aggregate + relu (one bucket per block, LDS accumulator)
  aggregate_kernel<<<nbuckets, 512, BROWS * UNITS * sizeof(float), stream>>>(
      boff, binned, h, out, n_nodes);
}

// Round 5
// 569.459 us; speedup vs baseline: 5.2810x; 5.2810x over previous
//
#include <hip/hip_runtime.h>
#include <hip/hip_fp16.h>

#define UNITS 128
#define IN_DIM 256
#define BK 32
#define BSHIFT 7                    // 128 rows per bucket
#define BROWS (1 << BSHIFT)
#define MAXBUCKETS 1024
#define BIN_CHUNK 4096              // edges per binning block

// ---------------------------------------------------------------------------
// GEMM: h = x @ W (fp32 compute, fp16 output).
// Block tile 64 rows x 128 cols, BK=32; per thread 8 rows x 4 cols.
// ---------------------------------------------------------------------------
__global__ __launch_bounds__(256) void gemm_xw_kernel(
    const float* __restrict__ x, const float* __restrict__ W,
    __half* __restrict__ h, int n_nodes) {
  __shared__ float Wt[BK * UNITS];   // 16 KiB  [kk][u]
  __shared__ float Xt[BK * 64];      // 8 KiB   [kk][r]

  const int tid = threadIdx.x;
  const int g   = tid & 31;
  const int tr  = tid >> 5;
  const int row0 = blockIdx.x * 64;

  float4 acc[8];
#pragma unroll
  for (int i = 0; i < 8; ++i) acc[i] = make_float4(0.f, 0.f, 0.f, 0.f);

  const int sr = tid & 63;
  const int cg = tid >> 6;
  const int grow = row0 + sr;

  for (int k0 = 0; k0 < IN_DIM; k0 += BK) {
    {
      const float4* Wg = (const float4*)(W + (size_t)k0 * UNITS);
      float4* Ws = (float4*)Wt;
#pragma unroll
      for (int i = 0; i < 4; ++i) Ws[tid + i * 256] = Wg[tid + i * 256];
    }
#pragma unroll
    for (int i = 0; i < 2; ++i) {
      const int c4 = cg + i * 4;
      float4 v = make_float4(0.f, 0.f, 0.f, 0.f);
      if (grow < n_nodes)
        v = *(const float4*)(x + (size_t)grow * IN_DIM + k0 + c4 * 4);
      Xt[(c4 * 4 + 0) * 64 + sr] = v.x;
      Xt[(c4 * 4 + 1) * 64 + sr] = v.y;
      Xt[(c4 * 4 + 2) * 64 + sr] = v.z;
      Xt[(c4 * 4 + 3) * 64 + sr] = v.w;
    }
    __syncthreads();

#pragma unroll 8
    for (int kk = 0; kk < BK; ++kk) {
      const float4 w  = ((const float4*)Wt)[kk * 32 + g];
      const float4 a0 = ((const float4*)Xt)[kk * 16 + tr * 2];
      const float4 a1 = ((const float4*)Xt)[kk * 16 + tr * 2 + 1];
      acc[0].x = fmaf(a0.x, w.x, acc[0].x); acc[0].y = fmaf(a0.x, w.y, acc[0].y);
      acc[0].z = fmaf(a0.x, w.z, acc[0].z); acc[0].w = fmaf(a0.x, w.w, acc[0].w);
      acc[1].x = fmaf(a0.y, w.x, acc[1].x); acc[1].y = fmaf(a0.y, w.y, acc[1].y);
      acc[1].z = fmaf(a0.y, w.z, acc[1].z); acc[1].w = fmaf(a0.y, w.w, acc[1].w);
      acc[2].x = fmaf(a0.z, w.x, acc[2].x); acc[2].y = fmaf(a0.z, w.y, acc[2].y);
      acc[2].z = fmaf(a0.z, w.z, acc[2].z); acc[2].w = fmaf(a0.z, w.w, acc[2].w);
      acc[3].x = fmaf(a0.w, w.x, acc[3].x); acc[3].y = fmaf(a0.w, w.y, acc[3].y);
      acc[3].z = fmaf(a0.w, w.z, acc[3].z); acc[3].w = fmaf(a0.w, w.w, acc[3].w);
      acc[4].x = fmaf(a1.x, w.x, acc[4].x); acc[4].y = fmaf(a1.x, w.y, acc[4].y);
      acc[4].z = fmaf(a1.x, w.z, acc[4].z); acc[4].w = fmaf(a1.x, w.w, acc[4].w);
      acc[5].x = fmaf(a1.y, w.x, acc[5].x); acc[5].y = fmaf(a1.y, w.y, acc[5].y);
      acc[5].z = fmaf(a1.y, w.z, acc[5].z); acc[5].w = fmaf(a1.y, w.w, acc[5].w);
      acc[6].x = fmaf(a1.z, w.x, acc[6].x); acc[6].y = fmaf(a1.z, w.y, acc[6].y);
      acc[6].z = fmaf(a1.z, w.z, acc[6].z); acc[6].w = fmaf(a1.z, w.w, acc[6].w);
      acc[7].x = fmaf(a1.w, w.x, acc[7].x); acc[7].y = fmaf(a1.w, w.y, acc[7].y);
      acc[7].z = fmaf(a1.w, w.z, acc[7].z); acc[7].w = fmaf(a1.w, w.w, acc[7].w);
    }
    __syncthreads();
  }

#pragma unroll
  for (int i = 0; i < 8; ++i) {
    const int rr = row0 + tr * 8 + i;
    if (rr < n_nodes) {
      union { __half2 h2[2]; uint2 u2; } pk;
      pk.h2[0] = __floats2half2_rn(acc[i].x, acc[i].y);
      pk.h2[1] = __floats2half2_rn(acc[i].z, acc[i].w);
      ((uint2*)(h + (size_t)rr * UNITS))[g] = pk.u2;
    }
  }
}

// ---------------------------------------------------------------------------
// Bucket histogram (LDS-aggregated, 782 counters)
// ---------------------------------------------------------------------------
__global__ __launch_bounds__(256) void bucket_hist_kernel(
    const int* __restrict__ rows, int* __restrict__ bhist,
    int n_edges, int nbuckets) {
  __shared__ int sh[MAXBUCKETS];
  const int tid = threadIdx.x;
  for (int i = tid; i < nbuckets; i += 256) sh[i] = 0;
  __syncthreads();
  const int stride = gridDim.x * blockDim.x;
  for (int e = blockIdx.x * blockDim.x + tid; e < n_edges; e += stride)
    atomicAdd(&sh[rows[e] >> BSHIFT], 1);
  __syncthreads();
  for (int i = tid; i < nbuckets; i += 256) {
    const int c = sh[i];
    if (c) atomicAdd(&bhist[i], c);
  }
}

// ---------------------------------------------------------------------------
// Bucket exclusive scan (single block; nbuckets <= 1024)
// ---------------------------------------------------------------------------
__global__ __launch_bounds__(1024) void bucket_scan_kernel(
    const int* __restrict__ bhist, int* __restrict__ boff,
    int* __restrict__ bcur, int nbuckets) {
  __shared__ int s[1024];
  const int t = threadIdx.x;
  const int v = (t < nbuckets) ? bhist[t] : 0;
  s[t] = v;
  __syncthreads();
  for (int off = 1; off < 1024; off <<= 1) {
    int u = 0;
    if (t >= off) u = s[t - off];
    __syncthreads();
    if (t >= off) s[t] += u;
    __syncthreads();
  }
  if (t < nbuckets) {
    boff[t] = s[t] - v;
    bcur[t] = s[t] - v;
  }
  if (t == 1023) boff[nbuckets] = s[1023];
}

// ---------------------------------------------------------------------------
// Binning: edges -> bucket-major order, packed (row_lo<<17 | col, valbits).
// 3-phase block-local LDS cursors => dense-ish appends.
// ---------------------------------------------------------------------------
__global__ __launch_bounds__(256) void binning_kernel(
    const int* __restrict__ rows, const int* __restrict__ cols,
    const float* __restrict__ vals, int* __restrict__ bcur,
    int2* __restrict__ binned, int n_edges, int nbuckets) {
  __shared__ int sh_hist[MAXBUCKETS];
  __shared__ int sh_base[MAXBUCKETS];
  const int tid = threadIdx.x;
  const int e0 = blockIdx.x * BIN_CHUNK;
  const int e_end = min(e0 + BIN_CHUNK, n_edges);

  for (int i = tid; i < nbuckets; i += 256) sh_hist[i] = 0;
  __syncthreads();
  for (int e = e0 + tid; e < e_end; e += 256)
    atomicAdd(&sh_hist[rows[e] >> BSHIFT], 1);
  __syncthreads();
  for (int i = tid; i < nbuckets; i += 256) {
    const int c = sh_hist[i];
    sh_base[i] = c ? atomicAdd(&bcur[i], c) : 0;
  }
  __syncthreads();
  for (int i = tid; i < nbuckets; i += 256) sh_hist[i] = 0;
  __syncthreads();
  for (int e = e0 + tid; e < e_end; e += 256) {
    const int r = rows[e];
    const int b = r >> BSHIFT;
    const int pos = sh_base[b] + atomicAdd(&sh_hist[b], 1);
    binned[pos] = make_int2(((r & (BROWS - 1)) << 17) | cols[e],
                            __float_as_int(vals[e]));
  }
}

// ---------------------------------------------------------------------------
// Row sort within bucket: one block per bucket. LDS hist+scan of 128 local
// rows, then rewrite edges row-sorted into spair (writes land in the bucket's
// own ~32KB window -> L2 line merge -> ~1x amplification). Emits row_start.
// ---------------------------------------------------------------------------
__global__ __launch_bounds__(256) void row_sort_kernel(
    const int* __restrict__ boff, const int2* __restrict__ binned,
    int2* __restrict__ spair, int* __restrict__ row_start,
    int n_nodes, int n_edges, int nbuckets) {
  __shared__ int hist[BROWS];
  __shared__ int scan[BROWS];
  __shared__ int cursor[BROWS];
  const int tid = threadIdx.x;
  const int b   = blockIdx.x;
  const int row0 = b << BSHIFT;
  const int e0 = boff[b];
  const int e1 = boff[b + 1];

  if (tid < BROWS) hist[tid] = 0;
  __syncthreads();

  for (int e = e0 + tid; e < e1; e += 256)
    atomicAdd(&hist[(binned[e].x >> 17) & (BROWS - 1)], 1);
  __syncthreads();

  // exclusive scan of 128 counts (Hillis-Steele, threads 0..127)
  if (tid < BROWS) scan[tid] = hist[tid];
  __syncthreads();
  for (int off = 1; off < BROWS; off <<= 1) {
    int u = 0;
    if (tid < BROWS && tid >= off) u = scan[tid - off];
    __syncthreads();
    if (tid < BROWS && tid >= off) scan[tid] += u;
    __syncthreads();
  }
  if (tid < BROWS) {
    const int excl = e0 + scan[tid] - hist[tid];
    cursor[tid] = excl;
    const int r = row0 + tid;
    if (r < n_nodes) row_start[r] = excl;
  }
  if (b == nbuckets - 1 && tid == 0) row_start[n_nodes] = n_edges;
  __syncthreads();

  for (int e = e0 + tid; e < e1; e += 256) {
    const int2 p = binned[e];
    const int rl = (p.x >> 17) & (BROWS - 1);
    const int pos = atomicAdd(&cursor[rl], 1);
    spair[pos] = make_int2(p.x & 0x1FFFF, p.y);
  }
}

// ---------------------------------------------------------------------------
// Aggregate: one wave per row, register accumulate, fp16 gathers, fused relu.
// ---------------------------------------------------------------------------
__global__ __launch_bounds__(256) void aggregate_kernel(
    const int* __restrict__ row_start, const int2* __restrict__ spair,
    const __half* __restrict__ h, float* __restrict__ out, int n_rows) {
  const int lane = threadIdx.x & 63;
  const int row  = (blockIdx.x * blockDim.x + threadIdx.x) >> 6;
  if (row >= n_rows) return;

  const int e0 = row_start[row];
  const int e1 = row_start[row + 1];

  float accx = 0.f, accy = 0.f;

  for (int base = e0; base < e1; base += 64) {
    const int m = min(64, e1 - base);
    int2 p = make_int2(0, 0);
    if (lane < m) p = spair[base + lane];
    for (int j = 0; j < m; ++j) {
      const int   cj = __shfl(p.x, j);
      const float vj = __int_as_float(__shfl(p.y, j));
      const __half2 g = ((const __half2*)(h + (size_t)cj * UNITS))[lane];
      const float2 f = __half22float2(g);
      accx = fmaf(vj, f.x, accx);
      accy = fmaf(vj, f.y, accy);
    }
  }

  float2 o;
  o.x = accx > 0.f ? accx : 0.f;
  o.y = accy > 0.f ? accy : 0.f;
  ((float2*)(out + (size_t)row * UNITS))[lane] = o;
}

// ---------------------------------------------------------------------------
extern "C" void kernel_launch(void* const* d_in, const int* in_sizes, int n_in,
                              void* d_out, int out_size, void* d_ws, size_t ws_size,
                              hipStream_t stream) {
  const float* x     = (const float*)d_in[0];
  const float* W     = (const float*)d_in[1];
  const int*   rows  = (const int*)d_in[2];
  const int*   cols  = (const int*)d_in[3];
  const float* vals  = (const float*)d_in[4];
  float*       out   = (float*)d_out;

  const int n_nodes = in_sizes[0] / IN_DIM;   // 100000
  const int n_edges = in_sizes[2];            // 3200000
  const int nbuckets = (n_nodes + BROWS - 1) >> BSHIFT;   // 782

  char* ws = (char*)d_ws;
  size_t off = 0;
  auto alloc = [&](size_t bytes) {
    char* p = ws + off;
    off += (bytes + 511) & ~(size_t)511;
    return p;
  };
  __half* h        = (__half*)alloc((size_t)n_nodes * UNITS * sizeof(__half)); // 25.6MB
  int*    bhist    = (int*)   alloc((size_t)nbuckets * sizeof(int));
  int*    boff     = (int*)   alloc((size_t)(nbuckets + 1) * sizeof(int));
  int*    bcur     = (int*)   alloc((size_t)nbuckets * sizeof(int));
  int*    row_start= (int*)   alloc((size_t)(n_nodes + 1) * sizeof(int));
  int2*   binned   = (int2*)  alloc((size_t)n_edges * sizeof(int2));           // 25.6MB
  int2*   spair    = (int2*)  alloc((size_t)n_edges * sizeof(int2));           // 25.6MB

  // 1) h = x @ W  (fp16 output)
  gemm_xw_kernel<<<(n_nodes + 63) / 64, 256, 0, stream>>>(x, W, h, n_nodes);

  // 2) bucket binning + within-bucket row sort (builds row-sorted CSR)
  hipMemsetAsync(bhist, 0, (size_t)nbuckets * sizeof(int), stream);
  bucket_hist_kernel<<<512, 256, 0, stream>>>(rows, bhist, n_edges, nbuckets);
  bucket_scan_kernel<<<1, 1024, 0, stream>>>(bhist, boff, bcur, nbuckets);
  binning_kernel<<<(n_edges + BIN_CHUNK - 1) / BIN_CHUNK, 256, 0, stream>>>(
      rows, cols, vals, bcur, binned, n_edges, nbuckets);
  row_sort_kernel<<<nbuckets, 256, 0, stream>>>(
      boff, binned, spair, row_start, n_nodes, n_edges, nbuckets);

  // 3) aggregate + relu (one wave per row, register accumulate)
  aggregate_kernel<<<(n_nodes * 64 + 255) / 256, 256, 0, stream>>>(
      row_start, spair, h, out, n_nodes);
}

// Round 6
// 558.466 us; speedup vs baseline: 5.3849x; 1.0197x over previous
//
#include <hip/hip_runtime.h>
#include <hip/hip_fp16.h>

#define UNITS 128
#define IN_DIM 256
#define BSHIFT 7                    // 128 rows per bucket
#define BROWS (1 << BSHIFT)
#define MAXBUCKETS 1024
#define BIN_CHUNK 4096              // edges per binning block

#define GR   64                     // gemm rows per block
#define GKC  64                     // gemm k-chunk
#define APAD 36                     // u32 per A row (32 data + 4 pad) -> 144B
#define BPAD 72                     // u16 per B row (64 data + 8 pad) -> 144B

typedef short bf16x8 __attribute__((ext_vector_type(8)));
typedef float f32x4  __attribute__((ext_vector_type(4)));
union FragU { uint4 u; bf16x8 f; };

__device__ inline unsigned short bf16_bits(float a) {
  unsigned u = __float_as_uint(a);
  return (unsigned short)((u + 0x7FFF + ((u >> 16) & 1)) >> 16);  // RNE
}
__device__ inline unsigned pack_bf16x2(float a, float b) {
  return (unsigned)bf16_bits(a) | ((unsigned)bf16_bits(b) << 16);
}

// ---------------------------------------------------------------------------
// GEMM: h = x @ W via bf16 MFMA (fp32->bf16 fused into LDS staging).
// Block: 64 rows x 128 cols, 4 waves (16 rows each), K-chunks of 64.
// A_lds [row][k] bf16 (pad 144B/row); B_lds [n][k] bf16 transposed (pad 144B).
// Frag maps (16x16x32): A: m=lane&15, k=(lane>>4)*8+j ; B: n=lane&15, same k;
// C/D: col=lane&15, row=(lane>>4)*4+reg   [verified m89/m91].
// ---------------------------------------------------------------------------
__global__ __launch_bounds__(256) void gemm_mfma_kernel(
    const float* __restrict__ x, const float* __restrict__ W,
    __half* __restrict__ h, int n_nodes) {
  __shared__ unsigned       A_lds[GR * APAD];     // 9216 B
  __shared__ unsigned short B_lds[UNITS * BPAD];  // 18432 B

  const int tid  = threadIdx.x;
  const int lane = tid & 63;
  const int wave = tid >> 6;          // 0..3
  const int row0 = blockIdx.x * GR;

  const int m    = lane & 15;
  const int quad = lane >> 4;         // 0..3

  f32x4 acc[8];
#pragma unroll
  for (int i = 0; i < 8; ++i) acc[i] = (f32x4){0.f, 0.f, 0.f, 0.f};

  for (int k0 = 0; k0 < IN_DIM; k0 += GKC) {
    // --- stage A: 64 rows x 64 k fp32 -> bf16. 1024 float4, 4 per thread.
#pragma unroll
    for (int p = 0; p < 4; ++p) {
      const int idx = tid + p * 256;
      const int r   = idx >> 4;        // 0..63
      const int c4  = idx & 15;        // float4 index within 64 k
      const int gr  = row0 + r;
      float4 v = make_float4(0.f, 0.f, 0.f, 0.f);
      if (gr < n_nodes)
        v = *(const float4*)(x + (size_t)gr * IN_DIM + k0 + c4 * 4);
      unsigned* dst = &A_lds[r * APAD + c4 * 2];
      dst[0] = pack_bf16x2(v.x, v.y);
      dst[1] = pack_bf16x2(v.z, v.w);
    }
    // --- stage B: 64 k x 128 n fp32 -> bf16, transposed to [n][k]. 8/thread.
#pragma unroll
    for (int p = 0; p < 8; ++p) {
      const int idx = tid + p * 256;
      const int k   = idx >> 5;        // 0..63
      const int n4  = idx & 31;        // float4 over n
      const float4 v = *(const float4*)(W + (size_t)(k0 + k) * UNITS + n4 * 4);
      B_lds[(n4 * 4 + 0) * BPAD + k] = bf16_bits(v.x);
      B_lds[(n4 * 4 + 1) * BPAD + k] = bf16_bits(v.y);
      B_lds[(n4 * 4 + 2) * BPAD + k] = bf16_bits(v.z);
      B_lds[(n4 * 4 + 3) * BPAD + k] = bf16_bits(v.w);
    }
    __syncthreads();

    // --- 2 MFMA K-steps of 32
#pragma unroll
    for (int ks = 0; ks < 2; ++ks) {
      FragU a;
      a.u = *(const uint4*)&A_lds[(wave * 16 + m) * APAD + ks * 16 + quad * 4];
#pragma unroll
      for (int nt = 0; nt < 8; ++nt) {
        FragU b;
        b.u = *(const uint4*)&B_lds[(nt * 16 + m) * BPAD + ks * 32 + quad * 8];
        acc[nt] = __builtin_amdgcn_mfma_f32_16x16x32_bf16(a.f, b.f, acc[nt], 0, 0, 0);
      }
    }
    __syncthreads();
  }

  // --- epilogue: fp16 h
  const int orow = row0 + wave * 16 + quad * 4;
#pragma unroll
  for (int nt = 0; nt < 8; ++nt) {
    const int col = nt * 16 + m;
#pragma unroll
    for (int i = 0; i < 4; ++i) {
      const int rr = orow + i;
      if (rr < n_nodes)
        h[(size_t)rr * UNITS + col] = __float2half(acc[nt][i]);
    }
  }
}

// ---------------------------------------------------------------------------
// Bucket histogram (LDS-aggregated, 782 counters)
// ---------------------------------------------------------------------------
__global__ __launch_bounds__(256) void bucket_hist_kernel(
    const int* __restrict__ rows, int* __restrict__ bhist,
    int n_edges, int nbuckets) {
  __shared__ int sh[MAXBUCKETS];
  const int tid = threadIdx.x;
  for (int i = tid; i < nbuckets; i += 256) sh[i] = 0;
  __syncthreads();
  const int stride = gridDim.x * blockDim.x;
  for (int e = blockIdx.x * blockDim.x + tid; e < n_edges; e += stride)
    atomicAdd(&sh[rows[e] >> BSHIFT], 1);
  __syncthreads();
  for (int i = tid; i < nbuckets; i += 256) {
    const int c = sh[i];
    if (c) atomicAdd(&bhist[i], c);
  }
}

// ---------------------------------------------------------------------------
// Bucket exclusive scan (single block; nbuckets <= 1024)
// ---------------------------------------------------------------------------
__global__ __launch_bounds__(1024) void bucket_scan_kernel(
    const int* __restrict__ bhist, int* __restrict__ boff,
    int* __restrict__ bcur, int nbuckets) {
  __shared__ int s[1024];
  const int t = threadIdx.x;
  const int v = (t < nbuckets) ? bhist[t] : 0;
  s[t] = v;
  __syncthreads();
  for (int off = 1; off < 1024; off <<= 1) {
    int u = 0;
    if (t >= off) u = s[t - off];
    __syncthreads();
    if (t >= off) s[t] += u;
    __syncthreads();
  }
  if (t < nbuckets) {
    boff[t] = s[t] - v;
    bcur[t] = s[t] - v;
  }
  if (t == 1023) boff[nbuckets] = s[1023];
}

// ---------------------------------------------------------------------------
// Binning: edges -> bucket-major order, packed (row_lo<<17 | col, valbits).
// ---------------------------------------------------------------------------
__global__ __launch_bounds__(256) void binning_kernel(
    const int* __restrict__ rows, const int* __restrict__ cols,
    const float* __restrict__ vals, int* __restrict__ bcur,
    int2* __restrict__ binned, int n_edges, int nbuckets) {
  __shared__ int sh_hist[MAXBUCKETS];
  __shared__ int sh_base[MAXBUCKETS];
  const int tid = threadIdx.x;
  const int e0 = blockIdx.x * BIN_CHUNK;
  const int e_end = min(e0 + BIN_CHUNK, n_edges);

  for (int i = tid; i < nbuckets; i += 256) sh_hist[i] = 0;
  __syncthreads();
  for (int e = e0 + tid; e < e_end; e += 256)
    atomicAdd(&sh_hist[rows[e] >> BSHIFT], 1);
  __syncthreads();
  for (int i = tid; i < nbuckets; i += 256) {
    const int c = sh_hist[i];
    sh_base[i] = c ? atomicAdd(&bcur[i], c) : 0;
  }
  __syncthreads();
  for (int i = tid; i < nbuckets; i += 256) sh_hist[i] = 0;
  __syncthreads();
  for (int e = e0 + tid; e < e_end; e += 256) {
    const int r = rows[e];
    const int b = r >> BSHIFT;
    const int pos = sh_base[b] + atomicAdd(&sh_hist[b], 1);
    binned[pos] = make_int2(((r & (BROWS - 1)) << 17) | cols[e],
                            __float_as_int(vals[e]));
  }
}

// ---------------------------------------------------------------------------
// Row sort within bucket: one block per bucket; emits row_start.
// ---------------------------------------------------------------------------
__global__ __launch_bounds__(256) void row_sort_kernel(
    const int* __restrict__ boff, const int2* __restrict__ binned,
    int2* __restrict__ spair, int* __restrict__ row_start,
    int n_nodes, int n_edges, int nbuckets) {
  __shared__ int hist[BROWS];
  __shared__ int scan[BROWS];
  __shared__ int cursor[BROWS];
  const int tid = threadIdx.x;
  const int b   = blockIdx.x;
  const int row0 = b << BSHIFT;
  const int e0 = boff[b];
  const int e1 = boff[b + 1];

  if (tid < BROWS) hist[tid] = 0;
  __syncthreads();

  for (int e = e0 + tid; e < e1; e += 256)
    atomicAdd(&hist[(binned[e].x >> 17) & (BROWS - 1)], 1);
  __syncthreads();

  if (tid < BROWS) scan[tid] = hist[tid];
  __syncthreads();
  for (int off = 1; off < BROWS; off <<= 1) {
    int u = 0;
    if (tid < BROWS && tid >= off) u = scan[tid - off];
    __syncthreads();
    if (tid < BROWS && tid >= off) scan[tid] += u;
    __syncthreads();
  }
  if (tid < BROWS) {
    const int excl = e0 + scan[tid] - hist[tid];
    cursor[tid] = excl;
    const int r = row0 + tid;
    if (r < n_nodes) row_start[r] = excl;
  }
  if (b == nbuckets - 1 && tid == 0) row_start[n_nodes] = n_edges;
  __syncthreads();

  for (int e = e0 + tid; e < e1; e += 256) {
    const int2 p = binned[e];
    const int rl = (p.x >> 17) & (BROWS - 1);
    const int pos = atomicAdd(&cursor[rl], 1);
    spair[pos] = make_int2(p.x & 0x1FFFF, p.y);
  }
}

// ---------------------------------------------------------------------------
// Aggregate: one wave per row, register accumulate, fp16 gathers, fused relu.
// ---------------------------------------------------------------------------
__global__ __launch_bounds__(256) void aggregate_kernel(
    const int* __restrict__ row_start, const int2* __restrict__ spair,
    const __half* __restrict__ h, float* __restrict__ out, int n_rows) {
  const int lane = threadIdx.x & 63;
  const int row  = (blockIdx.x * blockDim.x + threadIdx.x) >> 6;
  if (row >= n_rows) return;

  const int e0 = row_start[row];
  const int e1 = row_start[row + 1];

  float accx = 0.f, accy = 0.f;

  for (int base = e0; base < e1; base += 64) {
    const int m = min(64, e1 - base);
    int2 p = make_int2(0, 0);
    if (lane < m) p = spair[base + lane];
    for (int j = 0; j < m; ++j) {
      const int   cj = __shfl(p.x, j);
      const float vj = __int_as_float(__shfl(p.y, j));
      const __half2 g = ((const __half2*)(h + (size_t)cj * UNITS))[lane];
      const float2 f = __half22float2(g);
      accx = fmaf(vj, f.x, accx);
      accy = fmaf(vj, f.y, accy);
    }
  }

  float2 o;
  o.x = accx > 0.f ? accx : 0.f;
  o.y = accy > 0.f ? accy : 0.f;
  ((float2*)(out + (size_t)row * UNITS))[lane] = o;
}

// ---------------------------------------------------------------------------
extern "C" void kernel_launch(void* const* d_in, const int* in_sizes, int n_in,
                              void* d_out, int out_size, void* d_ws, size_t ws_size,
                              hipStream_t stream) {
  const float* x     = (const float*)d_in[0];
  const float* W     = (const float*)d_in[1];
  const int*   rows  = (const int*)d_in[2];
  const int*   cols  = (const int*)d_in[3];
  const float* vals  = (const float*)d_in[4];
  float*       out   = (float*)d_out;

  const int n_nodes = in_sizes[0] / IN_DIM;   // 100000
  const int n_edges = in_sizes[2];            // 3200000
  const int nbuckets = (n_nodes + BROWS - 1) >> BSHIFT;   // 782

  char* ws = (char*)d_ws;
  size_t off = 0;
  auto alloc = [&](size_t bytes) {
    char* p = ws + off;
    off += (bytes + 511) & ~(size_t)511;
    return p;
  };
  __half* h        = (__half*)alloc((size_t)n_nodes * UNITS * sizeof(__half)); // 25.6MB
  int*    bhist    = (int*)   alloc((size_t)nbuckets * sizeof(int));
  int*    boff     = (int*)   alloc((size_t)(nbuckets + 1) * sizeof(int));
  int*    bcur     = (int*)   alloc((size_t)nbuckets * sizeof(int));
  int*    row_start= (int*)   alloc((size_t)(n_nodes + 1) * sizeof(int));
  int2*   binned   = (int2*)  alloc((size_t)n_edges * sizeof(int2));           // 25.6MB
  int2*   spair    = (int2*)  alloc((size_t)n_edges * sizeof(int2));           // 25.6MB

  // 1) h = x @ W  (bf16 MFMA, fp16 output)
  gemm_mfma_kernel<<<(n_nodes + GR - 1) / GR, 256, 0, stream>>>(x, W, h, n_nodes);

  // 2) bucket binning + within-bucket row sort (builds row-sorted CSR)
  hipMemsetAsync(bhist, 0, (size_t)nbuckets * sizeof(int), stream);
  bucket_hist_kernel<<<512, 256, 0, stream>>>(rows, bhist, n_edges, nbuckets);
  bucket_scan_kernel<<<1, 1024, 0, stream>>>(bhist, boff, bcur, nbuckets);
  binning_kernel<<<(n_edges + BIN_CHUNK - 1) / BIN_CHUNK, 256, 0, stream>>>(
      rows, cols, vals, bcur, binned, n_edges, nbuckets);
  row_sort_kernel<<<nbuckets, 256, 0, stream>>>(
      boff, binned, spair, row_start, n_nodes, n_edges, nbuckets);

  // 3) aggregate + relu (one wave per row, register accumulate)
  aggregate_kernel<<<(n_nodes * 64 + 255) / 256, 256, 0, stream>>>(
      row_start, spair, h, out, n_nodes);
}

// Round 7
// 478.921 us; speedup vs baseline: 6.2793x; 1.1661x over previous
//
#include <hip/hip_runtime.h>
#include <hip/hip_fp16.h>

#define UNITS 128
#define IN_DIM 256
#define BSHIFT 7                    // 128 rows per bucket
#define BROWS (1 << BSHIFT)
#define MAXBUCKETS 1024
#define BIN_CHUNK 8192              // edges per binning block

#define GR   64                     // gemm rows per block
#define GKC  64                     // gemm k-chunk
#define APAD 36                     // u32 per A row (32 data + 4 pad) -> 144B
#define BPAD 72                     // u16 per B row (64 data + 8 pad) -> 144B

typedef short bf16x8 __attribute__((ext_vector_type(8)));
typedef float f32x4  __attribute__((ext_vector_type(4)));
union FragU { uint4 u; bf16x8 f; };

__device__ inline unsigned short bf16_bits(float a) {
  unsigned u = __float_as_uint(a);
  return (unsigned short)((u + 0x7FFF + ((u >> 16) & 1)) >> 16);  // RNE
}
__device__ inline unsigned pack_bf16x2(float a, float b) {
  return (unsigned)bf16_bits(a) | ((unsigned)bf16_bits(b) << 16);
}

// ---------------------------------------------------------------------------
// GEMM: h = x @ W via bf16 MFMA (fp32->bf16 fused into LDS staging).
// ---------------------------------------------------------------------------
__global__ __launch_bounds__(256) void gemm_mfma_kernel(
    const float* __restrict__ x, const float* __restrict__ W,
    __half* __restrict__ h, int n_nodes) {
  __shared__ unsigned       A_lds[GR * APAD];     // 9216 B
  __shared__ unsigned short B_lds[UNITS * BPAD];  // 18432 B

  const int tid  = threadIdx.x;
  const int lane = tid & 63;
  const int wave = tid >> 6;          // 0..3
  const int row0 = blockIdx.x * GR;

  const int m    = lane & 15;
  const int quad = lane >> 4;         // 0..3

  f32x4 acc[8];
#pragma unroll
  for (int i = 0; i < 8; ++i) acc[i] = (f32x4){0.f, 0.f, 0.f, 0.f};

  for (int k0 = 0; k0 < IN_DIM; k0 += GKC) {
#pragma unroll
    for (int p = 0; p < 4; ++p) {
      const int idx = tid + p * 256;
      const int r   = idx >> 4;
      const int c4  = idx & 15;
      const int gr  = row0 + r;
      float4 v = make_float4(0.f, 0.f, 0.f, 0.f);
      if (gr < n_nodes)
        v = *(const float4*)(x + (size_t)gr * IN_DIM + k0 + c4 * 4);
      unsigned* dst = &A_lds[r * APAD + c4 * 2];
      dst[0] = pack_bf16x2(v.x, v.y);
      dst[1] = pack_bf16x2(v.z, v.w);
    }
#pragma unroll
    for (int p = 0; p < 8; ++p) {
      const int idx = tid + p * 256;
      const int k   = idx >> 5;
      const int n4  = idx & 31;
      const float4 v = *(const float4*)(W + (size_t)(k0 + k) * UNITS + n4 * 4);
      B_lds[(n4 * 4 + 0) * BPAD + k] = bf16_bits(v.x);
      B_lds[(n4 * 4 + 1) * BPAD + k] = bf16_bits(v.y);
      B_lds[(n4 * 4 + 2) * BPAD + k] = bf16_bits(v.z);
      B_lds[(n4 * 4 + 3) * BPAD + k] = bf16_bits(v.w);
    }
    __syncthreads();

#pragma unroll
    for (int ks = 0; ks < 2; ++ks) {
      FragU a;
      a.u = *(const uint4*)&A_lds[(wave * 16 + m) * APAD + ks * 16 + quad * 4];
#pragma unroll
      for (int nt = 0; nt < 8; ++nt) {
        FragU b;
        b.u = *(const uint4*)&B_lds[(nt * 16 + m) * BPAD + ks * 32 + quad * 8];
        acc[nt] = __builtin_amdgcn_mfma_f32_16x16x32_bf16(a.f, b.f, acc[nt], 0, 0, 0);
      }
    }
    __syncthreads();
  }

  const int orow = row0 + wave * 16 + quad * 4;
#pragma unroll
  for (int nt = 0; nt < 8; ++nt) {
    const int col = nt * 16 + m;
#pragma unroll
    for (int i = 0; i < 4; ++i) {
      const int rr = orow + i;
      if (rr < n_nodes)
        h[(size_t)rr * UNITS + col] = __float2half(acc[nt][i]);
    }
  }
}

// ---------------------------------------------------------------------------
// Bucket histogram (LDS-aggregated, 782 counters)
// ---------------------------------------------------------------------------
__global__ __launch_bounds__(256) void bucket_hist_kernel(
    const int* __restrict__ rows, int* __restrict__ bhist,
    int n_edges, int nbuckets) {
  __shared__ int sh[MAXBUCKETS];
  const int tid = threadIdx.x;
  for (int i = tid; i < nbuckets; i += 256) sh[i] = 0;
  __syncthreads();
  const int stride = gridDim.x * blockDim.x;
  for (int e = blockIdx.x * blockDim.x + tid; e < n_edges; e += stride)
    atomicAdd(&sh[rows[e] >> BSHIFT], 1);
  __syncthreads();
  for (int i = tid; i < nbuckets; i += 256) {
    const int c = sh[i];
    if (c) atomicAdd(&bhist[i], c);
  }
}

// ---------------------------------------------------------------------------
// Bucket exclusive scan (single block; nbuckets <= 1024)
// ---------------------------------------------------------------------------
__global__ __launch_bounds__(1024) void bucket_scan_kernel(
    const int* __restrict__ bhist, int* __restrict__ boff,
    int* __restrict__ bcur, int nbuckets) {
  __shared__ int s[1024];
  const int t = threadIdx.x;
  const int v = (t < nbuckets) ? bhist[t] : 0;
  s[t] = v;
  __syncthreads();
  for (int off = 1; off < 1024; off <<= 1) {
    int u = 0;
    if (t >= off) u = s[t - off];
    __syncthreads();
    if (t >= off) s[t] += u;
    __syncthreads();
  }
  if (t < nbuckets) {
    boff[t] = s[t] - v;
    bcur[t] = s[t] - v;
  }
  if (t == 1023) boff[nbuckets] = s[1023];
}

// ---------------------------------------------------------------------------
// Binning: edges -> bucket-major order, packed (row_lo<<17 | col, valbits).
// ---------------------------------------------------------------------------
__global__ __launch_bounds__(256) void binning_kernel(
    const int* __restrict__ rows, const int* __restrict__ cols,
    const float* __restrict__ vals, int* __restrict__ bcur,
    int2* __restrict__ binned, int n_edges, int nbuckets) {
  __shared__ int sh_hist[MAXBUCKETS];
  __shared__ int sh_base[MAXBUCKETS];
  const int tid = threadIdx.x;
  const int e0 = blockIdx.x * BIN_CHUNK;
  const int e_end = min(e0 + BIN_CHUNK, n_edges);

  for (int i = tid; i < nbuckets; i += 256) sh_hist[i] = 0;
  __syncthreads();
  for (int e = e0 + tid; e < e_end; e += 256)
    atomicAdd(&sh_hist[rows[e] >> BSHIFT], 1);
  __syncthreads();
  for (int i = tid; i < nbuckets; i += 256) {
    const int c = sh_hist[i];
    sh_base[i] = c ? atomicAdd(&bcur[i], c) : 0;
  }
  __syncthreads();
  for (int i = tid; i < nbuckets; i += 256) sh_hist[i] = 0;
  __syncthreads();
  for (int e = e0 + tid; e < e_end; e += 256) {
    const int r = rows[e];
    const int b = r >> BSHIFT;
    const int pos = sh_base[b] + atomicAdd(&sh_hist[b], 1);
    binned[pos] = make_int2(((r & (BROWS - 1)) << 17) | cols[e],
                            __float_as_int(vals[e]));
  }
}

// ---------------------------------------------------------------------------
// Row sort within bucket: one block per bucket; emits row_start.
// ---------------------------------------------------------------------------
__global__ __launch_bounds__(256) void row_sort_kernel(
    const int* __restrict__ boff, const int2* __restrict__ binned,
    int2* __restrict__ spair, int* __restrict__ row_start,
    int n_nodes, int n_edges, int nbuckets) {
  __shared__ int hist[BROWS];
  __shared__ int scan[BROWS];
  __shared__ int cursor[BROWS];
  const int tid = threadIdx.x;
  const int b   = blockIdx.x;
  const int row0 = b << BSHIFT;
  const int e0 = boff[b];
  const int e1 = boff[b + 1];

  if (tid < BROWS) hist[tid] = 0;
  __syncthreads();

  for (int e = e0 + tid; e < e1; e += 256)
    atomicAdd(&hist[(binned[e].x >> 17) & (BROWS - 1)], 1);
  __syncthreads();

  if (tid < BROWS) scan[tid] = hist[tid];
  __syncthreads();
  for (int off = 1; off < BROWS; off <<= 1) {
    int u = 0;
    if (tid < BROWS && tid >= off) u = scan[tid - off];
    __syncthreads();
    if (tid < BROWS && tid >= off) scan[tid] += u;
    __syncthreads();
  }
  if (tid < BROWS) {
    const int excl = e0 + scan[tid] - hist[tid];
    cursor[tid] = excl;
    const int r = row0 + tid;
    if (r < n_nodes) row_start[r] = excl;
  }
  if (b == nbuckets - 1 && tid == 0) row_start[n_nodes] = n_edges;
  __syncthreads();

  for (int e = e0 + tid; e < e1; e += 256) {
    const int2 p = binned[e];
    const int rl = (p.x >> 17) & (BROWS - 1);
    const int pos = atomicAdd(&cursor[rl], 1);
    spair[pos] = make_int2(p.x & 0x1FFFF, p.y);
  }
}

// ---------------------------------------------------------------------------
// Aggregate: one wave per row. Batch of 64 edges staged in LDS (intra-wave,
// no barrier: DS ops are wave-ordered), inner loop unrolled x8 with
// zero-padded tail -> 8 independent gathers in flight. Fused relu.
// ---------------------------------------------------------------------------
__global__ __launch_bounds__(256) void aggregate_kernel(
    const int* __restrict__ row_start, const int2* __restrict__ spair,
    const __half* __restrict__ h, float* __restrict__ out, int n_rows) {
  __shared__ int2 stage[4][64];
  const int tid  = threadIdx.x;
  const int lane = tid & 63;
  const int wv   = tid >> 6;
  const int row  = (blockIdx.x * blockDim.x + tid) >> 6;
  if (row >= n_rows) return;

  const int e0 = row_start[row];
  const int e1 = row_start[row + 1];

  const __half2* hp = (const __half2*)h;   // UNITS/2 = 64 half2 per node row

  float accx = 0.f, accy = 0.f;

  for (int base = e0; base < e1; base += 64) {
    int m = e1 - base;
    if (m > 64) m = 64;
    int2 p = make_int2(0, 0);               // col=0, val=0 for padded lanes
    if (lane < m) p = spair[base + lane];
    stage[wv][lane] = p;                    // ds_write_b64 (wave-ordered)

    const int m_up = (m + 7) & ~7;
    for (int j = 0; j < m_up; j += 8) {
      float  v[8];
      float2 f[8];
#pragma unroll
      for (int u = 0; u < 8; ++u) {
        const int2 q = stage[wv][j + u];    // uniform-addr broadcast read
        v[u] = __int_as_float(q.y);
        f[u] = __half22float2(hp[(size_t)q.x * 64 + lane]);
      }
#pragma unroll
      for (int u = 0; u < 8; ++u) {
        accx = fmaf(v[u], f[u].x, accx);
        accy = fmaf(v[u], f[u].y, accy);
      }
    }
  }

  float2 o;
  o.x = accx > 0.f ? accx : 0.f;
  o.y = accy > 0.f ? accy : 0.f;
  ((float2*)(out + (size_t)row * UNITS))[lane] = o;
}

// ---------------------------------------------------------------------------
extern "C" void kernel_launch(void* const* d_in, const int* in_sizes, int n_in,
                              void* d_out, int out_size, void* d_ws, size_t ws_size,
                              hipStream_t stream) {
  const float* x     = (const float*)d_in[0];
  const float* W     = (const float*)d_in[1];
  const int*   rows  = (const int*)d_in[2];
  const int*   cols  = (const int*)d_in[3];
  const float* vals  = (const float*)d_in[4];
  float*       out   = (float*)d_out;

  const int n_nodes = in_sizes[0] / IN_DIM;   // 100000
  const int n_edges = in_sizes[2];            // 3200000
  const int nbuckets = (n_nodes + BROWS - 1) >> BSHIFT;   // 782

  char* ws = (char*)d_ws;
  size_t off = 0;
  auto alloc = [&](size_t bytes) {
    char* p = ws + off;
    off += (bytes + 511) & ~(size_t)511;
    return p;
  };
  __half* h        = (__half*)alloc((size_t)n_nodes * UNITS * sizeof(__half)); // 25.6MB
  int*    bhist    = (int*)   alloc((size_t)nbuckets * sizeof(int));
  int*    boff     = (int*)   alloc((size_t)(nbuckets + 1) * sizeof(int));
  int*    bcur     = (int*)   alloc((size_t)nbuckets * sizeof(int));
  int*    row_start= (int*)   alloc((size_t)(n_nodes + 1) * sizeof(int));
  int2*   binned   = (int2*)  alloc((size_t)n_edges * sizeof(int2));           // 25.6MB
  int2*   spair    = (int2*)  alloc((size_t)n_edges * sizeof(int2));           // 25.6MB

  // 1) h = x @ W  (bf16 MFMA, fp16 output)
  gemm_mfma_kernel<<<(n_nodes + GR - 1) / GR, 256, 0, stream>>>(x, W, h, n_nodes);

  // 2) bucket binning + within-bucket row sort (builds row-sorted CSR)
  hipMemsetAsync(bhist, 0, (size_t)nbuckets * sizeof(int), stream);
  bucket_hist_kernel<<<512, 256, 0, stream>>>(rows, bhist, n_edges, nbuckets);
  bucket_scan_kernel<<<1, 1024, 0, stream>>>(bhist, boff, bcur, nbuckets);
  binning_kernel<<<(n_edges + BIN_CHUNK - 1) / BIN_CHUNK, 256, 0, stream>>>(
      rows, cols, vals, bcur, binned, n_edges, nbuckets);
  row_sort_kernel<<<nbuckets, 256, 0, stream>>>(
      boff, binned, spair, row_start, n_nodes, n_edges, nbuckets);

  // 3) aggregate + relu (one wave per row, 8-deep gather pipeline)
  aggregate_kernel<<<(n_nodes * 64 + 255) / 256, 256, 0, stream>>>(
      row_start, spair, h, out, n_nodes);
}